// Round 16
// baseline (3033.282 us; speedup 1.0000x reference)
//
#include <hip/hip_runtime.h>
#include <math.h>

// ---------------- problem dims ----------------
#define BB 8
#define RR 12
#define WIDTH 2304
#define TT 4
#define HH 16
#define WW 29
#define HWIN (HH*WW)        // 464
#define REDUCE 1024
#define HID 512
#define NC 60
#define DEPTH 2
#define NIMG (BB*RR)        // 96
#define OH2 14
#define OW2 27
#define NSP2 (OH2*OW2)      // 378
#define PH 7
#define PW 14
#define NSP (PH*PW)         // 98
#define ATT_SCALE 0.044194173824159216f

typedef __attribute__((ext_vector_type(8))) short short8;
typedef __attribute__((ext_vector_type(4))) float floatx4;

// ---------------- helpers ----------------
__device__ __forceinline__ void split2(float v, unsigned short& h, unsigned short& l)
{
    union { float f; unsigned u; } c; c.f = v;
    unsigned hb = c.u & 0xffff0000u;
    h = (unsigned short)(hb >> 16);
    union { float f; unsigned u; } hc; hc.u = hb;
    float r = v - hc.f;
    union { float f; unsigned u; } rc; rc.f = r;
    unsigned ru = rc.u + 0x7fffu + ((rc.u >> 16) & 1u);
    l = (unsigned short)(ru >> 16);
}

__device__ __forceinline__ void gll16(const void* g, void* l)
{
    __builtin_amdgcn_global_load_lds((const __attribute__((address_space(1))) void*)g,
                                     (__attribute__((address_space(3))) void*)l,
                                     16, 0, 0);
}

#define MFMA3(d, ah_, al_, bh_, bl_) \
    d = __builtin_amdgcn_mfma_f32_16x16x32_bf16(ah_, bh_, d, 0, 0, 0); \
    d = __builtin_amdgcn_mfma_f32_16x16x32_bf16(ah_, bl_, d, 0, 0, 0); \
    d = __builtin_amdgcn_mfma_f32_16x16x32_bf16(al_, bh_, d, 0, 0, 0);

// ================= tapr_k: ci-block-major, z-grouped 3x3 conv GEMM (champion) =================
// K-order: kst = cb*9 + tap. Weights [kst*4+g][512][8] bf16 hi (+ lo at +294912 int4).
// B tile per cb: [zi ZB][pl 2][lrow 4][WR] int4, serves ALL 9 taps via shifted LDS reads.
// TYPE 0: hr2o pad-1 conv, plane [z][160][512]; TYPE 1: conv2 valid, [z][472][512].
template<int TYPE, int NSEL, bool RELU, bool RESID, int WR, int ZB>
__global__ __launch_bounds__(256, 2)
void tapr_k(const int4* __restrict__ WA0, const int4* __restrict__ WA1, const int4* __restrict__ WA2,
            const ushort* __restrict__ BH, const ushort* __restrict__ BL,
            const float* __restrict__ Res,
            float* __restrict__ Y0, float* __restrict__ Y1, float* __restrict__ Y2)
{
    __shared__ int4 L[2064 + ZB * 8 * WR];
    const int tid = threadIdx.x;
    constexpr int NZP = 96 / ZB;

    int ch, zp, nb = 0;
    if (TYPE == 0) { ch = blockIdx.x / NZP; zp = blockIdx.x % NZP; }
    else { ch = blockIdx.x / (4 * NZP); int r = blockIdx.x % (4 * NZP); nb = r / NZP; zp = r % NZP; }
    int sel = 0, m0;
    if (NSEL == 3) { sel = ch >> 2; m0 = (ch & 3) * 128; }
    else m0 = ch * 128;
    const int z0 = zp * ZB;

    const int4* WA = (NSEL == 3) ? (sel == 0 ? WA0 : sel == 1 ? WA1 : WA2) : WA0;
    float* Y = (NSEL == 3) ? (sel == 0 ? Y0 : sel == 1 ? Y1 : Y2) : Y0;

    const int lane = tid & 63, wv = tid >> 6;
    const int lrow = lane >> 4, lcol = lane & 15;
    constexpr long ALO = 294912;
    constexpr long PLSTR = (TYPE == 1) ? 472L * 512 : 160L * 512;
    const int pbase = (TYPE == 1) ? (((nb * 112) >> 5) * 29 + ((nb * 112) & 31)) : 0;

    int pbnf[7];
#pragma unroll
    for (int nf = 0; nf < 7; ++nf) {
        int col = nf * 16 + lcol;
        if (TYPE == 0) pbnf[nf] = col;
        else { int gn = nb * 112 + col; pbnf[nf] = (gn >> 5) * 29 + (gn & 31) - pbase; }
    }

    int uR[3], uPl[3], uZi[3]; bool uV[3];
    const ushort* uSrc[3];
#pragma unroll
    for (int it = 0; it < 3; ++it) {
        int u = tid + it * 256;
        uV[it] = (u < 2 * ZB * WR);
        int uu = uV[it] ? u : 0;
        uR[it] = uu % WR; uPl[it] = (uu / WR) & 1; uZi[it] = uu / (2 * WR);
        const ushort* P = uPl[it] ? BL : BH;
        uSrc[it] = P + (size_t)(z0 + uZi[it]) * PLSTR + (size_t)(pbase + uR[it]) * 512;
    }

    floatx4 acc[ZB][2][7];
#pragma unroll
    for (int zi = 0; zi < ZB; ++zi)
#pragma unroll
        for (int mf = 0; mf < 2; ++mf)
#pragma unroll
            for (int nf = 0; nf < 7; ++nf) acc[zi][mf][nf] = (floatx4){0.f, 0.f, 0.f, 0.f};

#define BCOPY(CB) { \
    _Pragma("unroll") \
    for (int it = 0; it < 3; ++it) if (uV[it]) { \
        const int4* s = (const int4*)(uSrc[it] + (size_t)(CB) * 32); \
        int4 t0 = s[0], t1 = s[1], t2 = s[2], t3_ = s[3]; \
        int bse = 2064 + uZi[it] * (8 * WR) + uPl[it] * (4 * WR) + uR[it]; \
        L[bse] = t0; L[bse + WR] = t1; L[bse + 2 * WR] = t2; L[bse + 3 * WR] = t3_; \
    } }

#define ASTAGE(KST, BUF) { \
    int k8 = (KST) * 4; \
    _Pragma("unroll") \
    for (int j = 0; j < 4; ++j) { \
        int h = wv * 4 + j, p = h >> 3, g = (h >> 1) & 3, hf = h & 1; \
        gll16(WA + (p ? ALO : 0) + (long)(k8 + g) * 512 + m0 + hf * 64 + lane, \
              L + (BUF) * 1032 + (p * 4 + g) * 129 + hf * 64); \
    } }

#define COMPUTE(BUF, SHV) { \
    const int4* La = L + (BUF) * 1032; \
    short8 ah[2], al[2]; \
    _Pragma("unroll") \
    for (int mf = 0; mf < 2; ++mf) { \
        int au = lrow * 129 + (wv * 2 + mf) * 16 + lcol; \
        ah[mf] = *(const short8*)(La + au); \
        al[mf] = *(const short8*)(La + 516 + au); \
    } \
    _Pragma("unroll") \
    for (int nf = 0; nf < 7; ++nf) { \
        int spl = pbnf[nf] + (SHV); \
        _Pragma("unroll") \
        for (int zi = 0; zi < ZB; ++zi) { \
            const int4* Lb = L + 2064 + zi * (8 * WR) + lrow * WR + spl; \
            short8 bh = *(const short8*)(Lb); \
            short8 bl = *(const short8*)(Lb + 4 * WR); \
            _Pragma("unroll") \
            for (int mf = 0; mf < 2; ++mf) { MFMA3(acc[zi][mf][nf], ah[mf], al[mf], bh, bl) } \
        } \
    } }

    BCOPY(0)
    ASTAGE(0, 0)
    __syncthreads();

    int cur = 0;
    for (int cb = 0; cb < 16; ++cb) {
#pragma unroll
        for (int tap = 0; tap < 9; ++tap) {
            const int kst = cb * 9 + tap;
            const int t3 = tap / 3;
            const int shv = (TYPE == 0) ? (t3 * 16 + (tap - t3 * 3)) : (t3 * 29 + (tap - t3 * 3));
            if (kst < 143) ASTAGE(kst + 1, cur ^ 1)
            COMPUTE(cur, shv)
            __syncthreads();
            cur ^= 1;
        }
        if (cb < 15) {
            BCOPY(cb + 1)
            __syncthreads();
        }
    }

    // epilogue
#pragma unroll
    for (int zi = 0; zi < ZB; ++zi) {
        const int z = z0 + zi;
#pragma unroll
        for (int mf = 0; mf < 2; ++mf) {
            int m = m0 + wv * 32 + mf * 16 + lrow * 4;
#pragma unroll
            for (int nf = 0; nf < 7; ++nf) {
                int col = nf * 16 + lcol;
                int sp, realn; bool ok;
                if (TYPE == 0) { int oh = col >> 4, ow = col & 15; ok = ow < 14; sp = oh * 14 + ow; realn = 98; }
                else { int gn = nb * 112 + col; int oh = gn >> 5, ow = gn & 31; ok = ow < 27; sp = oh * 27 + ow; realn = 378; }
                if (ok) {
#pragma unroll
                    for (int r = 0; r < 4; ++r) {
                        size_t idx = ((size_t)z * 512 + m + r) * realn + sp;
                        float v = acc[zi][mf][nf][r];
                        if (RESID) v += Res[idx];
                        if (RELU) v = fmaxf(v, 0.f);
                        Y[idx] = v;
                    }
                }
            }
        }
    }
#undef BCOPY
#undef ASTAGE
#undef COMPUTE
}

// ================= tapr5_k: A-direct-from-global, B-only-LDS, barrier-per-cb (cw) =================
// TYPE 0, ZB=1, single A register set. Per kst: 4 global dwordx4 (A frags, coalesced 256B
// segments, L2/L3-resident) + 14 ds_read_b128 (B) + 42 MFMA; barriers ONLY around the
// per-cb BCOPY (2 per 9 ksts vs 11 in tapr_k). acc=56 +A 16 +temps ~110 VGPR < 128 cap.
// LDS = 8*WR int4 (20.6 KB). Grid = 4 ch x 96 z (z-fastest for chunk L2 adjacency).
template<bool RELU, bool RESID, int WR>
__global__ __launch_bounds__(256, 2)
void tapr5_k(const int4* __restrict__ WA,
             const ushort* __restrict__ BH, const ushort* __restrict__ BL,
             const float* __restrict__ Res, float* __restrict__ Y)
{
    __shared__ int4 L[8 * WR];
    const int tid = threadIdx.x;
    const int ch = blockIdx.x / 96, z = blockIdx.x % 96;
    const int m0 = ch * 128;
    const int lane = tid & 63, wv = tid >> 6;
    const int lrow = lane >> 4, lcol = lane & 15;
    constexpr long ALO = 294912;
    constexpr long PLSTR = 160L * 512;

    // B copy units: u = tid + it*256 < 2*WR
    bool uV[2]; int uR[2], uPl[2];
    const ushort* uSrc[2];
#pragma unroll
    for (int it = 0; it < 2; ++it) {
        int u = tid + it * 256;
        uV[it] = (u < 2 * WR);
        int uu = uV[it] ? u : 0;
        uR[it] = uu % WR; uPl[it] = uu / WR;
        uSrc[it] = (uPl[it] ? BL : BH) + (size_t)z * PLSTR + (size_t)uR[it] * 512;
    }

    // A fragment base: WA[kst*2048 + lrow*512 + m0 + wv*32 + mf*16 + lcol]
    const long abase0 = (long)lrow * 512 + m0 + wv * 32 + lcol;

    floatx4 acc[2][7];
#pragma unroll
    for (int mf = 0; mf < 2; ++mf)
#pragma unroll
        for (int nf = 0; nf < 7; ++nf) acc[mf][nf] = (floatx4){0.f, 0.f, 0.f, 0.f};

    short8 ah[2], al[2];

#define BCOPY5(CB) { \
    _Pragma("unroll") \
    for (int it = 0; it < 2; ++it) if (uV[it]) { \
        const int4* s = (const int4*)(uSrc[it] + (size_t)(CB) * 32); \
        int4 t0 = s[0], t1 = s[1], t2 = s[2], t3_ = s[3]; \
        int bse = uPl[it] * (4 * WR) + uR[it]; \
        L[bse] = t0; L[bse + WR] = t1; L[bse + 2 * WR] = t2; L[bse + 3 * WR] = t3_; \
    } }

#define ALOAD5(KST) { \
    long ab = (long)(KST) * 2048 + abase0; \
    _Pragma("unroll") \
    for (int mf = 0; mf < 2; ++mf) { \
        ah[mf] = *(const short8*)(WA + ab + mf * 16); \
        al[mf] = *(const short8*)(WA + ALO + ab + mf * 16); \
    } }

#define COMPUTE5(SHV) { \
    _Pragma("unroll") \
    for (int nf = 0; nf < 7; ++nf) { \
        int spl = nf * 16 + lcol + (SHV); \
        const int4* Lb = L + lrow * WR + spl; \
        short8 bh = *(const short8*)(Lb); \
        short8 bl = *(const short8*)(Lb + 4 * WR); \
        _Pragma("unroll") \
        for (int mf = 0; mf < 2; ++mf) { MFMA3(acc[mf][nf], ah[mf], al[mf], bh, bl) } \
    } }

    BCOPY5(0)
    __syncthreads();

    for (int cb = 0; cb < 16; ++cb) {
#pragma unroll
        for (int tap = 0; tap < 9; ++tap) {
            const int t3 = tap / 3;
            const int shv = t3 * 16 + (tap - t3 * 3);
            ALOAD5(cb * 9 + tap)
            COMPUTE5(shv)
        }
        if (cb < 15) {
            __syncthreads();      // all waves done reading B(cb)
            BCOPY5(cb + 1)
            __syncthreads();      // B(cb+1) visible
        }
    }

    // epilogue
#pragma unroll
    for (int mf = 0; mf < 2; ++mf) {
        int m = m0 + wv * 32 + mf * 16 + lrow * 4;
#pragma unroll
        for (int nf = 0; nf < 7; ++nf) {
            int col = nf * 16 + lcol;
            int oh = col >> 4, ow = col & 15;
            if (ow < 14) {
                int sp = oh * 14 + ow;
#pragma unroll
                for (int r = 0; r < 4; ++r) {
                    size_t idx = ((size_t)z * 512 + m + r) * 98 + sp;
                    float v = acc[mf][nf][r];
                    if (RESID) v += Res[idx];
                    if (RELU) v = fmaxf(v, 0.f);
                    Y[idx] = v;
                }
            }
        }
    }
#undef BCOPY5
#undef ALOAD5
#undef COMPUTE5
}

// ---------------- plain-GEMM split-bf16 MFMA (reduce / bg), 3D grid ----------------
template<int KW, int KSTN, int MTOT, long PLSTR, int NREAL>
__global__ __launch_bounds__(256, 2)
void tapc_k(const int4* __restrict__ WA,
            const ushort* __restrict__ BH, const ushort* __restrict__ BL,
            float* __restrict__ Y)
{
    __shared__ int4 L[3872];
    const int tid = threadIdx.x;
    const int z = blockIdx.z, nb = blockIdx.x;
    const int m0 = blockIdx.y * 128;
    const int lane = tid & 63, wv = tid >> 6;
    const int lrow = lane >> 4, lcol = lane & 15;
    constexpr long ALO = (long)KSTN * 4 * MTOT;

    int nU[2], gU[2]; long pbU[2]; bool vU[2];
#pragma unroll
    for (int it = 0; it < 2; ++it) {
        int u = tid + (it << 8);
        vU[it] = (u < 448);
        int uu = vU[it] ? u : 0;
        nU[it] = uu % 112; gU[it] = uu / 112;
        int gn = nb * 112 + nU[it];
        pbU[it] = min(gn, NREAL - 1);
    }
    const ushort* BHz = BH + (size_t)z * PLSTR;
    const ushort* BLz = BL + (size_t)z * PLSTR;

    floatx4 acc[2][7];
#pragma unroll
    for (int mf = 0; mf < 2; ++mf)
#pragma unroll
        for (int nf = 0; nf < 7; ++nf) acc[mf][nf] = (floatx4){0.f, 0.f, 0.f, 0.f};

    short8 rbh[2], rbl[2];

#define STAGE_ISSUE(KST, BUF) { \
    int k8 = (KST) * 4; \
    _Pragma("unroll") \
    for (int j = 0; j < 4; ++j) { \
        int h = wv * 4 + j, p = h >> 3, g = (h >> 1) & 3, hf = h & 1; \
        gll16(WA + (p ? ALO : 0) + (long)(k8 + g) * MTOT + m0 + hf * 64 + lane, \
              L + (BUF) * 1936 + (p * 4 + g) * 129 + hf * 64); \
    } \
    int ci0 = (KST) << 5; \
    _Pragma("unroll") \
    for (int it = 0; it < 2; ++it) if (vU[it]) { \
        size_t o = (size_t)pbU[it] * KW + ci0 + gU[it] * 8; \
        rbh[it] = *(const short8*)(BHz + o); \
        rbl[it] = *(const short8*)(BLz + o); \
    } }

#define STAGE_WRITE(BUF) { \
    _Pragma("unroll") \
    for (int it = 0; it < 2; ++it) if (vU[it]) { \
        *((short8*)(L + (BUF) * 1936 + 1032 + gU[it] * 113 + nU[it])) = rbh[it]; \
        *((short8*)(L + (BUF) * 1936 + 1484 + gU[it] * 113 + nU[it])) = rbl[it]; \
    } }

#define COMPUTE(BUF) { \
    const int4* Lc = L + (BUF) * 1936; \
    short8 ah[2], al[2]; \
    _Pragma("unroll") \
    for (int mf = 0; mf < 2; ++mf) { \
        int au = lrow * 129 + (wv * 2 + mf) * 16 + lcol; \
        ah[mf] = *(const short8*)(Lc + au); \
        al[mf] = *(const short8*)(Lc + 516 + au); \
    } \
    _Pragma("unroll") \
    for (int nf = 0; nf < 7; ++nf) { \
        int bu = 1032 + lrow * 113 + nf * 16 + lcol; \
        short8 bh = *(const short8*)(Lc + bu); \
        short8 bl = *(const short8*)(Lc + bu + 452); \
        _Pragma("unroll") \
        for (int mf = 0; mf < 2; ++mf) { MFMA3(acc[mf][nf], ah[mf], al[mf], bh, bl) } \
    } }

    STAGE_ISSUE(0, 0)
    STAGE_WRITE(0)
    __syncthreads();

    int cur = 0;
    for (int kst = 0; kst < KSTN; ++kst) {
        int nxt = cur ^ 1;
        bool more = (kst + 1 < KSTN);
        if (more) STAGE_ISSUE(kst + 1, nxt)
        COMPUTE(cur)
        if (more) { STAGE_WRITE(nxt) __syncthreads(); }
        cur = nxt;
    }

#pragma unroll
    for (int mf = 0; mf < 2; ++mf) {
        int m = m0 + wv * 32 + mf * 16 + lrow * 4;
#pragma unroll
        for (int nf = 0; nf < 7; ++nf) {
            int col = nf * 16 + lcol;
            int gn = nb * 112 + col;
            if (gn < NREAL) {
#pragma unroll
                for (int r = 0; r < 4; ++r) {
                    size_t idx = ((size_t)z * MTOT + m + r) * NREAL + gn;
                    Y[idx] = acc[mf][nf][r];
                }
            }
        }
    }
#undef STAGE_ISSUE
#undef STAGE_WRITE
#undef COMPUTE
}

// ---- weight prep: 3x3 convs [512][ci*9+tap] -> [576][512][8] hi/lo, K-order (cb,tap,ci) ----
__global__ void prep_w_k(const float* __restrict__ s0, const float* __restrict__ s1,
                         const float* __restrict__ s2, const float* __restrict__ s3,
                         int4* __restrict__ dst)
{
    const int c = blockIdx.y;
    const float* src = (c == 0) ? s0 : (c == 1) ? s1 : (c == 2) ? s2 : s3;
    int4* dh = dst + (size_t)c * 589824;
    int4* dl = dh + 294912;
    int idx = blockIdx.x * 256 + threadIdx.x;
    if (idx >= 294912) return;
    int g8 = idx / 512, m = idx & 511;
    unsigned hw[4], lw[4];
#pragma unroll
    for (int j = 0; j < 4; ++j) {
        int k1 = g8 * 8 + 2 * j, k2 = k1 + 1;
        int cb1 = k1 / 288, r1 = k1 % 288, tp1 = r1 >> 5, ci1 = cb1 * 32 + (r1 & 31);
        int cb2 = k2 / 288, r2 = k2 % 288, tp2 = r2 >> 5, ci2 = cb2 * 32 + (r2 & 31);
        float v1 = src[(size_t)m * 4608 + ci1 * 9 + tp1];
        float v2 = src[(size_t)m * 4608 + ci2 * 9 + tp2];
        unsigned short h0, l0, h1, l1;
        split2(v1, h0, l0); split2(v2, h1, l1);
        hw[j] = (unsigned)h0 | ((unsigned)h1 << 16);
        lw[j] = (unsigned)l0 | ((unsigned)l1 << 16);
    }
    dh[idx] = make_int4(hw[0], hw[1], hw[2], hw[3]);
    dl[idx] = make_int4(lw[0], lw[1], lw[2], lw[3]);
}

// ---------------- weight prep: plain GEMM A [M][ldw] -> [K/8][M][8] hi/lo ----------------
__global__ void prep_wg_k(const float* __restrict__ src, int ldw, int M, int K8,
                          int4* __restrict__ dst)
{
    int idx = blockIdx.x * 256 + threadIdx.x;
    if (idx >= K8 * M) return;
    int g8 = idx / M, m = idx % M;
    unsigned hw[4], lw[4];
#pragma unroll
    for (int j = 0; j < 4; ++j) {
        int k1 = g8 * 8 + 2 * j;
        float v1 = src[(size_t)m * ldw + k1];
        float v2 = src[(size_t)m * ldw + k1 + 1];
        unsigned short h0, l0, h1, l1;
        split2(v1, h0, l0); split2(v2, h1, l1);
        hw[j] = (unsigned)h0 | ((unsigned)h1 << 16);
        lw[j] = (unsigned)l0 | ((unsigned)l1 << 16);
    }
    dst[idx] = make_int4(hw[0], hw[1], hw[2], hw[3]);
    dst[(size_t)K8 * M + idx] = make_int4(lw[0], lw[1], lw[2], lw[3]);
}

// ---------------- transpose + split: src [C][S] fp32 -> dst [S][C] bf16 hi/lo ----------------
__global__ __launch_bounds__(256)
void tsplit_k(const float* __restrict__ src, ushort* __restrict__ dh, ushort* __restrict__ dl,
              int C, int S, long zsrc, long zdst)
{
    __shared__ float t[64][65];
    const int c0 = blockIdx.x * 64, s0 = blockIdx.y * 64, z = blockIdx.z;
    const float* sz = src + (size_t)z * zsrc;
    const int tx = threadIdx.x & 63, ty = threadIdx.x >> 6;
#pragma unroll
    for (int i = 0; i < 16; ++i) {
        int cc = i * 4 + ty;
        int c = c0 + cc, s = s0 + tx;
        t[cc][tx] = (c < C && s < S) ? sz[(size_t)c * S + s] : 0.f;
    }
    __syncthreads();
#pragma unroll
    for (int i = 0; i < 16; ++i) {
        int ss = i * 4 + ty;
        int s = s0 + ss, c = c0 + tx;
        if (s < S && c < C) {
            unsigned short h, l;
            split2(t[tx][ss], h, l);
            size_t o = (size_t)z * zdst + (size_t)s * C + c;
            dh[o] = h; dl[o] = l;
        }
    }
}

// ---------------- conv2 B prestage: relu(bg[b] + bias1[z])^T -> [z][472][512] hi/lo ----------------
__global__ __launch_bounds__(256)
void tsplit_c2_k(const float* __restrict__ bg, const float* __restrict__ bias1,
                 ushort* __restrict__ dh, ushort* __restrict__ dl)
{
    __shared__ float t[64][65];
    const int c0 = blockIdx.x * 64, s0 = blockIdx.y * 64, z = blockIdx.z;
    const int b = z / RR;
    const int tx = threadIdx.x & 63, ty = threadIdx.x >> 6;
#pragma unroll
    for (int i = 0; i < 16; ++i) {
        int cc = i * 4 + ty;
        int s = s0 + tx;
        t[cc][tx] = (s < 464) ? bg[((size_t)b * 512 + c0 + cc) * 464 + s] : 0.f;
    }
    __syncthreads();
    const float bv = bias1[z * 512 + c0 + tx];
#pragma unroll
    for (int i = 0; i < 16; ++i) {
        int ss = i * 4 + ty;
        int s = s0 + ss, c = c0 + tx;
        if (s < 472) {
            float v = (s < 464) ? fmaxf(t[tx][ss] + bv, 0.f) : 0.f;
            unsigned short h, l;
            split2(v, h, l);
            size_t o = (size_t)z * 241664 + (size_t)s * 512 + c;
            dh[o] = h; dl[o] = l;
        }
    }
}

// ---------------- hr2o B prestage: pad 7x14 -> [z][160 sp][512 ci] hi/lo ----------------
__global__ __launch_bounds__(256)
void tsplit_pad_k(const float* __restrict__ x, ushort* __restrict__ dh, ushort* __restrict__ dl)
{
    __shared__ float t[64 * 99];
    const int c0 = blockIdx.x * 64, z = blockIdx.y;
    const int tid = threadIdx.x;
#pragma unroll
    for (int i = 0; i < 25; ++i) {
        int idx = tid + i * 256;
        if (idx < 6272) {
            int c = idx / 98, s = idx % 98;
            t[c * 99 + s] = x[((size_t)z * 512 + c0 + c) * 98 + s];
        }
    }
    __syncthreads();
#pragma unroll
    for (int i = 0; i < 40; ++i) {
        int idx = tid + i * 256;   // < 10240 = 160*64
        int sp = idx >> 6, c = idx & 63;
        int r = sp >> 4, col = sp & 15;
        float v = (r >= 1 && r <= 7 && col >= 1 && col <= 14) ? t[c * 99 + (r - 1) * 14 + col - 1] : 0.f;
        unsigned short h, l;
        split2(v, h, l);
        size_t o = (size_t)z * 81920 + (size_t)sp * 512 + c0 + c;
        dh[o] = h; dl[o] = l;
    }
}

// ---------------- temporal mean ----------------
__global__ void tmean_k(const float* __restrict__ f, float* __restrict__ o, int total)
{
    int i = blockIdx.x * blockDim.x + threadIdx.x;
    if (i >= total) return;
    int p = i % HWIN; long bc = i / HWIN;
    const float* src = f + bc * (long)TT * HWIN + p;
    o[i] = (src[0] + src[HWIN] + src[2 * HWIN] + src[3 * HWIN]) * 0.25f;
}

// ---------------- ROI align ----------------
__global__ __launch_bounds__(256)
void roi_align_k(const float* __restrict__ feats, const float* __restrict__ rois,
                 float* __restrict__ roi_feats)
{
    __shared__ int s_o00[196], s_o01[196], s_o10[196], s_o11[196];
    __shared__ float s_w[4][196];
    const int n = blockIdx.x;
    const int b = n / RR;
    const int t = threadIdx.x;
    if (t < 196) {
        float x1 = rois[n * 4 + 0] * WW, y1 = rois[n * 4 + 1] * HH;
        float x2 = rois[n * 4 + 2] * WW, y2 = rois[n * 4 + 3] * HH;
        float rw = fmaxf(x2 - x1, 1.f), rh = fmaxf(y2 - y1, 1.f);
        float bw = rw / 7.f, bh = rh / 7.f;
        int j = t / 14, i = t % 14;
        float gy = (float)(j >> 1) + ((j & 1) + 0.5f) * 0.5f;
        float gx = (float)(i >> 1) + ((i & 1) + 0.5f) * 0.5f;
        float ys = y1 + gy * bh, xs = x1 + gx * bw;
        bool valid = (ys >= -1.f) && (ys <= (float)HH) && (xs >= -1.f) && (xs <= (float)WW);
        float y = fminf(fmaxf(ys, 0.f), (float)(HH - 1));
        float x = fminf(fmaxf(xs, 0.f), (float)(WW - 1));
        float y0f = floorf(y), x0f = floorf(x);
        int iy0 = (int)y0f, ix0 = (int)x0f;
        int iy1 = min(iy0 + 1, HH - 1), ix1 = min(ix0 + 1, WW - 1);
        float ly = y - y0f, lx = x - x0f, hy = 1.f - ly, hx = 1.f - lx;
        float msk = valid ? 1.f : 0.f;
        s_o00[t] = iy0 * WW + ix0; s_o01[t] = iy0 * WW + ix1;
        s_o10[t] = iy1 * WW + ix0; s_o11[t] = iy1 * WW + ix1;
        s_w[0][t] = hy * hx * msk; s_w[1][t] = hy * lx * msk;
        s_w[2][t] = ly * hx * msk; s_w[3][t] = ly * lx * msk;
    }
    __syncthreads();
    for (int c = t; c < REDUCE; c += 256) {
        const float* img = feats + ((long)(b * REDUCE + c)) * HWIN;
        float mx = -INFINITY;
        for (int bin = 0; bin < 49; ++bin) {
            int by_ = bin / 7, bx = bin % 7;
            float s = 0.f;
#pragma unroll
            for (int sy = 0; sy < 2; ++sy)
#pragma unroll
                for (int sx = 0; sx < 2; ++sx) {
                    int ss = (by_ * 2 + sy) * 14 + bx * 2 + sx;
                    s += s_w[0][ss] * img[s_o00[ss]] + s_w[1][ss] * img[s_o01[ss]]
                       + s_w[2][ss] * img[s_o10[ss]] + s_w[3][ss] * img[s_o11[ss]];
                }
            mx = fmaxf(mx, s * 0.25f);
        }
        roi_feats[(long)n * REDUCE + c] = mx;
    }
}

// ---------------- small dense dots ----------------
__global__ void dots_k(const float* __restrict__ Xr, const float* __restrict__ Wt,
                       int ldw, int woff, float* __restrict__ Y,
                       int Nrows, int M, int K, int relu)
{
    int idx = blockIdx.x * blockDim.x + threadIdx.x;
    if (idx >= Nrows * M) return;
    int o = idx / Nrows, n = idx % Nrows;
    const float* xr = Xr + (long)n * K;
    const float* w = Wt + (long)o * ldw + woff;
    float acc = 0.f;
    for (int k = 0; k < K; ++k) acc = fmaf(xr[k], w[k], acc);
    if (relu) acc = fmaxf(acc, 0.f);
    Y[(long)n * M + o] = acc;
}

// ---------------- maxpool 3x3 s2 pad1 ----------------
__global__ void maxpool_k(const float* __restrict__ in, float* __restrict__ out, int total)
{
    int idx = blockIdx.x * blockDim.x + threadIdx.x;
    if (idx >= total) return;
    int ow = idx % PW; int r = idx / PW; int oh = r % PH; long nc = r / PH;
    const float* src = in + nc * NSP2;
    float m = -INFINITY;
    for (int kh = 0; kh < 3; ++kh) {
        int ih = oh * 2 - 1 + kh; if (ih < 0 || ih >= OH2) continue;
        for (int kw = 0; kw < 3; ++kw) {
            int iw = ow * 2 - 1 + kw; if (iw < 0 || iw >= OW2) continue;
            m = fmaxf(m, src[ih * OW2 + iw]);
        }
    }
    out[idx] = m;
}

// ---------------- fused attention scores + softmax ----------------
__global__ __launch_bounds__(256)
void att2_k(const float* __restrict__ q, const float* __restrict__ k, float* __restrict__ att)
{
    __shared__ float qs[5376];
    __shared__ float ks[5376];
    __shared__ float sc[1008];
    const int b = blockIdx.x, p0 = blockIdx.y * 7;
    const int tid = threadIdx.x;

    int itI[4], itJ[4], itP[4]; bool itV[4];
#pragma unroll
    for (int r = 0; r < 4; ++r) {
        int item = tid + (r << 8);
        itV[r] = item < 1008;
        int it = itV[r] ? item : 0;
        int ij = it / 7; itP[r] = it % 7;
        itI[r] = ij / 12; itJ[r] = ij % 12;
    }
    float acc[4] = {0.f, 0.f, 0.f, 0.f};

    for (int cc0 = 0; cc0 < 512; cc0 += 64) {
        for (int l = tid; l < 5376; l += 256) {
            int i = l / 448, r = l % 448, c = r / 7, p = r % 7;
            size_t off = ((size_t)(b * 12 + i) * 512 + cc0 + c) * 98 + p0 + p;
            qs[l] = q[off];
            ks[l] = k[off];
        }
        __syncthreads();
#pragma unroll
        for (int r = 0; r < 4; ++r) {
            if (itV[r]) {
                const float* qp = qs + itI[r] * 448 + itP[r];
                const float* kp = ks + itJ[r] * 448 + itP[r];
                float a = acc[r];
#pragma unroll 8
                for (int c = 0; c < 64; ++c) a = fmaf(qp[c * 7], kp[c * 7], a);
                acc[r] = a;
            }
        }
        __syncthreads();
    }
#pragma unroll
    for (int r = 0; r < 4; ++r)
        if (itV[r]) sc[tid + (r << 8)] = acc[r] * ATT_SCALE;
    __syncthreads();
    if (tid < 84) {
        int i = tid / 7, p = tid % 7;
        float m = -INFINITY;
        float v[12];
#pragma unroll
        for (int j = 0; j < 12; ++j) { v[j] = sc[(i * 12 + j) * 7 + p]; m = fmaxf(m, v[j]); }
        float s = 0.f;
#pragma unroll
        for (int j = 0; j < 12; ++j) { v[j] = expf(v[j] - m); s += v[j]; }
        float inv = 1.f / s;
#pragma unroll
        for (int j = 0; j < 12; ++j)
            att[((size_t)(b * 12 + i) * 12 + j) * 98 + p0 + p] = v[j] * inv;
    }
}

// ---------------- virt = att @ v ----------------
__global__ __launch_bounds__(256)
void virt2_k(const float* __restrict__ att, const float* __restrict__ v, float* __restrict__ virt)
{
    __shared__ float as_[14112];
    const int b = blockIdx.x, cb = blockIdx.y;
    const int tid = threadIdx.x;
    for (int l = tid; l < 14112; l += 256) as_[l] = att[(size_t)b * 14112 + l];
    __syncthreads();

    for (int it = tid; it < 6272; it += 256) {
        int c = cb * 64 + it / 98, p = it % 98;
        float o[12];
#pragma unroll
        for (int i = 0; i < 12; ++i) o[i] = 0.f;
#pragma unroll
        for (int j = 0; j < 12; ++j) {
            float vj = v[((size_t)(b * 12 + j) * 512 + c) * 98 + p];
#pragma unroll
            for (int i = 0; i < 12; ++i) o[i] = fmaf(as_[(i * 12 + j) * 98 + p], vj, o[i]);
        }
#pragma unroll
        for (int i = 0; i < 12; ++i)
            virt[((size_t)(b * 12 + i) * 512 + c) * 98 + p] = o[i];
    }
}

// ---------------- per-actor stats ----------------
__global__ __launch_bounds__(256)
void stats_k(const float* __restrict__ virt, float* __restrict__ mu, float* __restrict__ rstd)
{
    int n = blockIdx.x;
    const float* src = virt + (long)n * HID * NSP;
    float s = 0.f, q = 0.f;
    for (int i = threadIdx.x; i < HID * NSP; i += 256) {
        float v = src[i]; s += v; q = fmaf(v, v, q);
    }
    for (int off = 32; off; off >>= 1) { s += __shfl_down(s, off); q += __shfl_down(q, off); }
    __shared__ float ss[4], sq[4];
    int w = threadIdx.x >> 6;
    if ((threadIdx.x & 63) == 0) { ss[w] = s; sq[w] = q; }
    __syncthreads();
    if (threadIdx.x == 0) {
        float S = ss[0] + ss[1] + ss[2] + ss[3];
        float Q = sq[0] + sq[1] + sq[2] + sq[3];
        const float invN = 1.f / (HID * NSP);
        float m = S * invN;
        float var = Q * invN - m * m;
        mu[n] = m; rstd[n] = rsqrtf(var + 1e-5f);
    }
}

// ---------------- normalize + affine + relu ----------------
__global__ void norm_k(float* __restrict__ virt, const float* __restrict__ mu,
                       const float* __restrict__ rstd,
                       const float* __restrict__ gamma, const float* __restrict__ beta)
{
    int idx = blockIdx.x * blockDim.x + threadIdx.x;
    const int TOT = NIMG * HID * NSP;
    if (idx >= TOT) return;
    int n = idx / (HID * NSP);
    int c = (idx / NSP) % HID;
    float val = (virt[idx] - mu[n]) * rstd[n] * gamma[c] + beta[c];
    virt[idx] = fmaxf(val, 0.f);
}

// ---------------- spatial mean ----------------
__global__ void meanpool_k(const float* __restrict__ x, float* __restrict__ high)
{
    int idx = blockIdx.x * blockDim.x + threadIdx.x;
    if (idx >= NIMG * HID) return;
    const float* src = x + (long)idx * NSP;
    float s = 0.f;
    for (int p = 0; p < NSP; ++p) s += src[p];
    high[idx] = s * (1.f / NSP);
}

// ---------------- final FC ----------------
__global__ void final_k(const float* __restrict__ fc1o, const float* __restrict__ high,
                        const float* __restrict__ fc2, float* __restrict__ out)
{
    int idx = blockIdx.x * blockDim.x + threadIdx.x;
    if (idx >= NIMG * NC) return;
    int n = idx / NC, o = idx % NC;
    const float* w = fc2 + (long)o * (2 * HID);
    const float* a = fc1o + (long)n * HID;
    const float* h = high + (long)n * HID;
    float acc = 0.f;
    for (int c = 0; c < HID; ++c) acc = fmaf(a[c], w[c], acc);
    for (int c = 0; c < HID; ++c) acc = fmaf(h[c], w[HID + c], acc);
    out[idx] = acc;
}

// ---------------- launcher ----------------
extern "C" void kernel_launch(void* const* d_in, const int* in_sizes, int n_in,
                              void* d_out, int out_size, void* d_ws, size_t ws_size,
                              hipStream_t stream)
{
    (void)in_sizes; (void)n_in; (void)out_size; (void)ws_size;
    const float* features = (const float*)d_in[0];
    const float* rois     = (const float*)d_in[1];
    const float* w_reduce = (const float*)d_in[2];
    const float* w_conv1  = (const float*)d_in[3];
    const float* w_conv2  = (const float*)d_in[4];
    const float* qw       = (const float*)d_in[5];
    const float* kw       = (const float*)d_in[6];
    const float* vw       = (const float*)d_in[7];
    const float* cw       = (const float*)d_in[8];
    const float* gamma    = (const float*)d_in[9];
    const float* beta     = (const float*)d_in[10];
    const float* fc1      = (const float*)d_in[11];
    const float* fc2      = (const float*)d_in[12];
    float* ws = (float*)d_ws;

    // ---- workspace layout (floats), high-water ~62.0M = 248 MB ----
    float*  tmean = ws + 0;
    ushort* tmTH  = (ushort*)(ws + 8552448);
    ushort* tmTL  = (ushort*)(ws + 12828672);
    float*  feats = ws + 17104896;
    ushort* ftTH  = (ushort*)(ws + 0);
    ushort* ftTL  = (ushort*)(ws + 1900544);
    ushort* B2H   = (ushort*)(ws + 0);
    ushort* B2L   = (ushort*)(ws + 11599872);
    int4*   WTQ   = (int4*)(ws + 0);
    float*  bg    = ws + 23199744;
    float*  out2  = ws + 23199744;
    float*  qb    = ws + 23199744;
    float*  kb    = ws + 28016640;
    float*  vb    = ws + 32833536;
    ushort* PTH   = (ushort*)(ws + 41779200);
    ushort* PTL   = (ushort*)(ws + 45711360);
    float*  xb    = ws + 49643520;
    float*  virt  = ws + 54460416;
    int4*   WTS   = (int4*)(ws + 59277312);
    float*  rf    = ws + 61636608;
    float*  bias1 = ws + 61734912;
    float*  fc1o  = ws + 61784064;
    float*  attb  = ws + 61833216;
    float*  mu    = ws + 61946112;
    float*  rstd  = ws + 61946240;
    float*  high  = ws + 61946368;

    dim3 blk(256);

    // 0. reduce-conv weight prep
    prep_wg_k<<<1152, blk, 0, stream>>>(w_reduce, 2304, 1024, 288, WTS);

    // 1. temporal mean
    { int tot = BB * WIDTH * HWIN;
      tmean_k<<<(tot + 255) / 256, blk, 0, stream>>>(features, tmean, tot); }

    // 2. transpose+split tmean
    tsplit_k<<<dim3(36, 8, 8), blk, 0, stream>>>(tmean, tmTH, tmTL, 2304, 464, 1069056, 1069056);

    // 3. reduce conv (MFMA GEMM)
    tapc_k<2304, 72, 1024, 464L * 2304, 464>
        <<<dim3(5, 8, 8), blk, 0, stream>>>(WTS, tmTH, tmTL, feats);

    // 4. transpose+split feats
    tsplit_k<<<dim3(16, 8, 8), blk, 0, stream>>>(feats, ftTH, ftTL, 1024, 464, 475136, 475136);

    // 5. ROI align + actor bias + fc1
    roi_align_k<<<96, blk, 0, stream>>>(feats, rois, rf);
    dots_k<<<(NIMG * HID + 255) / 256, blk, 0, stream>>>(rf, w_conv1, 2048, 1024, bias1, NIMG, HID, REDUCE, 0);
    dots_k<<<(NIMG * HID + 255) / 256, blk, 0, stream>>>(rf, fc1, 1024, 0, fc1o, NIMG, HID, REDUCE, 1);

    // 6. bg GEMM
    prep_wg_k<<<256, blk, 0, stream>>>(w_conv1, 2048, 512, 128, WTS);
    tapc_k<1024, 32, 512, 464L * 1024, 464>
        <<<dim3(5, 4, 8), blk, 0, stream>>>(WTS, ftTH, ftTL, bg);

    // 7. conv2 weight prep (cb-tap-ci order) + B prestage
    prep_w_k<<<dim3(1152, 1), blk, 0, stream>>>(w_conv2, w_conv2, w_conv2, w_conv2, WTS);
    tsplit_c2_k<<<dim3(8, 8, 96), blk, 0, stream>>>(bg, bias1, B2H, B2L);

    // 8. conv2: champion config (768 blocks: 4 ch x 4 nb x 48 zp)
    tapr_k<1, 1, true, false, 165, 2><<<768, blk, 0, stream>>>(
        WTS, nullptr, nullptr, B2H, B2L, nullptr, out2, nullptr, nullptr);

    // 9. maxpool
    { int tot = NIMG * HID * NSP;
      maxpool_k<<<(tot + 255) / 256, blk, 0, stream>>>(out2, xb, tot); }

    // 10. HR2O layers
    for (int d = 0; d < DEPTH; ++d) {
        long woff = (long)d * HID * HID * 9;
        prep_w_k<<<dim3(1152, 4), blk, 0, stream>>>(qw + woff, kw + woff, vw + woff, cw + woff, WTQ);

        tsplit_pad_k<<<dim3(8, 96), blk, 0, stream>>>(xb, PTH, PTL);
        // qkv: champion config (576 blocks: 12 ch x 48 zp)
        tapr_k<0, 3, false, false, 161, 2><<<576, blk, 0, stream>>>(
            WTQ, WTQ + 589824, WTQ + 2 * 589824, PTH, PTL, nullptr, qb, kb, vb);

        att2_k<<<dim3(8, 14), blk, 0, stream>>>(qb, kb, attb);
        virt2_k<<<dim3(8, 8), blk, 0, stream>>>(attb, vb, virt);
        stats_k<<<96, blk, 0, stream>>>(virt, mu, rstd);
        { int tot = NIMG * HID * NSP;
          norm_k<<<(tot + 255) / 256, blk, 0, stream>>>(virt, mu, rstd, gamma + d * HID, beta + d * HID); }

        tsplit_pad_k<<<dim3(8, 96), blk, 0, stream>>>(virt, PTH, PTL);
        // cw: NEW tapr5 (A-direct, B-only LDS, 2 barriers/cb; 384 blocks = 4 ch x 96 z)
        tapr5_k<false, true, 161><<<384, blk, 0, stream>>>(
            WTQ + 3 * 589824, PTH, PTL, xb, xb);
    }

    // 11. spatial mean + final FC
    meanpool_k<<<(NIMG * HID + 255) / 256, blk, 0, stream>>>(xb, high);
    final_k<<<(NIMG * NC + 255) / 256, blk, 0, stream>>>(fc1o, high, fc2, (float*)d_out);
}

// Round 17
// 2930.070 us; speedup vs baseline: 1.0352x; 1.0352x over previous
//
#include <hip/hip_runtime.h>
#include <math.h>

// ---------------- problem dims ----------------
#define BB 8
#define RR 12
#define WIDTH 2304
#define TT 4
#define HH 16
#define WW 29
#define HWIN (HH*WW)        // 464
#define REDUCE 1024
#define HID 512
#define NC 60
#define DEPTH 2
#define NIMG (BB*RR)        // 96
#define OH2 14
#define OW2 27
#define NSP2 (OH2*OW2)      // 378
#define PH 7
#define PW 14
#define NSP (PH*PW)         // 98
#define ATT_SCALE 0.044194173824159216f

typedef __attribute__((ext_vector_type(8))) short short8;
typedef __attribute__((ext_vector_type(4))) float floatx4;

// ---------------- helpers ----------------
__device__ __forceinline__ void split2(float v, unsigned short& h, unsigned short& l)
{
    union { float f; unsigned u; } c; c.f = v;
    unsigned hb = c.u & 0xffff0000u;
    h = (unsigned short)(hb >> 16);
    union { float f; unsigned u; } hc; hc.u = hb;
    float r = v - hc.f;
    union { float f; unsigned u; } rc; rc.f = r;
    unsigned ru = rc.u + 0x7fffu + ((rc.u >> 16) & 1u);
    l = (unsigned short)(ru >> 16);
}

__device__ __forceinline__ void gll16(const void* g, void* l)
{
    __builtin_amdgcn_global_load_lds((const __attribute__((address_space(1))) void*)g,
                                     (__attribute__((address_space(3))) void*)l,
                                     16, 0, 0);
}

#define MFMA3(d, ah_, al_, bh_, bl_) \
    d = __builtin_amdgcn_mfma_f32_16x16x32_bf16(ah_, bh_, d, 0, 0, 0); \
    d = __builtin_amdgcn_mfma_f32_16x16x32_bf16(ah_, bl_, d, 0, 0, 0); \
    d = __builtin_amdgcn_mfma_f32_16x16x32_bf16(al_, bh_, d, 0, 0, 0);

// ================= tapr_k: ci-block-major, z-grouped 3x3 conv GEMM (champion) =================
// K-order: kst = cb*9 + tap. Weights [kst*4+g][512][8] bf16 hi (+ lo at +294912 int4).
// B tile per cb: [zi ZB][pl 2][lrow 4][WR] int4, serves ALL 9 taps via shifted LDS reads.
// TYPE 0: hr2o pad-1 conv, plane [z][160][512]; TYPE 1: conv2 valid, [z][472][512].
// ZB: z's per block. KSP: K-split factor (1 = full K; 2 = half-K partials, no RELU/RESID,
// output selected by kh into Y0/Y1; grid MUST be KSP * NSELCH*4 * NZP).
template<int TYPE, int NSEL, bool RELU, bool RESID, int WR, int ZB, int KSP>
__global__ __launch_bounds__(256, 2)
void tapr_k(const int4* __restrict__ WA0, const int4* __restrict__ WA1, const int4* __restrict__ WA2,
            const ushort* __restrict__ BH, const ushort* __restrict__ BL,
            const float* __restrict__ Res,
            float* __restrict__ Y0, float* __restrict__ Y1, float* __restrict__ Y2)
{
    __shared__ int4 L[2064 + ZB * 8 * WR];
    const int tid = threadIdx.x;
    constexpr int NZP = 96 / ZB;

    int ch, zp, nb = 0, kh = 0;
    if (TYPE == 0) {
        int b = blockIdx.x;
        if (KSP == 2) { kh = b / (4 * NZP); b %= (4 * NZP); }
        ch = b / NZP; zp = b % NZP;
    } else {
        ch = blockIdx.x / (4 * NZP); int r = blockIdx.x % (4 * NZP); nb = r / NZP; zp = r % NZP;
    }
    int sel = 0, m0;
    if (NSEL == 3) { sel = ch >> 2; m0 = (ch & 3) * 128; }
    else m0 = ch * 128;
    const int z0 = zp * ZB;
    const int cb0 = (KSP == 2) ? kh * 8 : 0;
    const int cb1 = (KSP == 2) ? cb0 + 8 : 16;

    const int4* WA = (NSEL == 3) ? (sel == 0 ? WA0 : sel == 1 ? WA1 : WA2) : WA0;
    float* Y = (KSP == 2) ? (kh == 0 ? Y0 : Y1)
             : ((NSEL == 3) ? (sel == 0 ? Y0 : sel == 1 ? Y1 : Y2) : Y0);

    const int lane = tid & 63, wv = tid >> 6;
    const int lrow = lane >> 4, lcol = lane & 15;
    constexpr long ALO = 294912;
    constexpr long PLSTR = (TYPE == 1) ? 472L * 512 : 160L * 512;
    const int pbase = (TYPE == 1) ? (((nb * 112) >> 5) * 29 + ((nb * 112) & 31)) : 0;

    // per-thread B fragment col bases (pb - pbase) for nf = 0..6
    int pbnf[7];
#pragma unroll
    for (int nf = 0; nf < 7; ++nf) {
        int col = nf * 16 + lcol;
        if (TYPE == 0) pbnf[nf] = col;
        else { int gn = nb * 112 + col; pbnf[nf] = (gn >> 5) * 29 + (gn & 31) - pbase; }
    }

    // B copy units: u = it*256+tid < 2*ZB*WR ; r = u%WR, pl = (u/WR)&1, zi = u/(2*WR)
    int uR[3], uPl[3], uZi[3]; bool uV[3];
    const ushort* uSrc[3];
#pragma unroll
    for (int it = 0; it < 3; ++it) {
        int u = tid + it * 256;
        uV[it] = (u < 2 * ZB * WR);
        int uu = uV[it] ? u : 0;
        uR[it] = uu % WR; uPl[it] = (uu / WR) & 1; uZi[it] = uu / (2 * WR);
        const ushort* P = uPl[it] ? BL : BH;
        uSrc[it] = P + (size_t)(z0 + uZi[it]) * PLSTR + (size_t)(pbase + uR[it]) * 512;
    }

    floatx4 acc[ZB][2][7];
#pragma unroll
    for (int zi = 0; zi < ZB; ++zi)
#pragma unroll
        for (int mf = 0; mf < 2; ++mf)
#pragma unroll
            for (int nf = 0; nf < 7; ++nf) acc[zi][mf][nf] = (floatx4){0.f, 0.f, 0.f, 0.f};

#define BCOPY(CB) { \
    _Pragma("unroll") \
    for (int it = 0; it < 3; ++it) if (uV[it]) { \
        const int4* s = (const int4*)(uSrc[it] + (size_t)(CB) * 32); \
        int4 t0 = s[0], t1 = s[1], t2 = s[2], t3_ = s[3]; \
        int bse = 2064 + uZi[it] * (8 * WR) + uPl[it] * (4 * WR) + uR[it]; \
        L[bse] = t0; L[bse + WR] = t1; L[bse + 2 * WR] = t2; L[bse + 3 * WR] = t3_; \
    } }

#define ASTAGE(KST, BUF) { \
    int k8 = (KST) * 4; \
    _Pragma("unroll") \
    for (int j = 0; j < 4; ++j) { \
        int h = wv * 4 + j, p = h >> 3, g = (h >> 1) & 3, hf = h & 1; \
        gll16(WA + (p ? ALO : 0) + (long)(k8 + g) * 512 + m0 + hf * 64 + lane, \
              L + (BUF) * 1032 + (p * 4 + g) * 129 + hf * 64); \
    } }

#define COMPUTE(BUF, SHV) { \
    const int4* La = L + (BUF) * 1032; \
    short8 ah[2], al[2]; \
    _Pragma("unroll") \
    for (int mf = 0; mf < 2; ++mf) { \
        int au = lrow * 129 + (wv * 2 + mf) * 16 + lcol; \
        ah[mf] = *(const short8*)(La + au); \
        al[mf] = *(const short8*)(La + 516 + au); \
    } \
    _Pragma("unroll") \
    for (int nf = 0; nf < 7; ++nf) { \
        int spl = pbnf[nf] + (SHV); \
        _Pragma("unroll") \
        for (int zi = 0; zi < ZB; ++zi) { \
            const int4* Lb = L + 2064 + zi * (8 * WR) + lrow * WR + spl; \
            short8 bh = *(const short8*)(Lb); \
            short8 bl = *(const short8*)(Lb + 4 * WR); \
            _Pragma("unroll") \
            for (int mf = 0; mf < 2; ++mf) { MFMA3(acc[zi][mf][nf], ah[mf], al[mf], bh, bl) } \
        } \
    } }

    // prologue: B(cb0) + A(first kst)
    BCOPY(cb0)
    ASTAGE(cb0 * 9, 0)
    __syncthreads();

    int cur = 0;
    for (int cb = cb0; cb < cb1; ++cb) {
#pragma unroll
        for (int tap = 0; tap < 9; ++tap) {
            const int kst = cb * 9 + tap;
            const int t3 = tap / 3;
            const int shv = (TYPE == 0) ? (t3 * 16 + (tap - t3 * 3)) : (t3 * 29 + (tap - t3 * 3));
            if (kst < cb1 * 9 - 1) ASTAGE(kst + 1, cur ^ 1)
            COMPUTE(cur, shv)
            __syncthreads();
            cur ^= 1;
        }
        if (cb < cb1 - 1) {
            BCOPY(cb + 1)
            __syncthreads();
        }
    }

    // epilogue
#pragma unroll
    for (int zi = 0; zi < ZB; ++zi) {
        const int z = z0 + zi;
#pragma unroll
        for (int mf = 0; mf < 2; ++mf) {
            int m = m0 + wv * 32 + mf * 16 + lrow * 4;
#pragma unroll
            for (int nf = 0; nf < 7; ++nf) {
                int col = nf * 16 + lcol;
                int sp, realn; bool ok;
                if (TYPE == 0) { int oh = col >> 4, ow = col & 15; ok = ow < 14; sp = oh * 14 + ow; realn = 98; }
                else { int gn = nb * 112 + col; int oh = gn >> 5, ow = gn & 31; ok = ow < 27; sp = oh * 27 + ow; realn = 378; }
                if (ok) {
#pragma unroll
                    for (int r = 0; r < 4; ++r) {
                        size_t idx = ((size_t)z * 512 + m + r) * realn + sp;
                        float v = acc[zi][mf][nf][r];
                        if (RESID) v += Res[idx];
                        if (RELU) v = fmaxf(v, 0.f);
                        Y[idx] = v;
                    }
                }
            }
        }
    }
#undef BCOPY
#undef ASTAGE
#undef COMPUTE
}

// ---------------- split-K merge: xb += p0 + p1 ----------------
__global__ void merge_k(float* __restrict__ xb, const float* __restrict__ p0,
                        const float* __restrict__ p1, int total)
{
    int idx = blockIdx.x * blockDim.x + threadIdx.x;
    if (idx >= total) return;
    xb[idx] = xb[idx] + (p0[idx] + p1[idx]);
}

// ---------------- plain-GEMM split-bf16 MFMA (reduce / bg), 3D grid ----------------
template<int KW, int KSTN, int MTOT, long PLSTR, int NREAL>
__global__ __launch_bounds__(256, 2)
void tapc_k(const int4* __restrict__ WA,
            const ushort* __restrict__ BH, const ushort* __restrict__ BL,
            float* __restrict__ Y)
{
    __shared__ int4 L[3872];
    const int tid = threadIdx.x;
    const int z = blockIdx.z, nb = blockIdx.x;
    const int m0 = blockIdx.y * 128;
    const int lane = tid & 63, wv = tid >> 6;
    const int lrow = lane >> 4, lcol = lane & 15;
    constexpr long ALO = (long)KSTN * 4 * MTOT;

    int nU[2], gU[2]; long pbU[2]; bool vU[2];
#pragma unroll
    for (int it = 0; it < 2; ++it) {
        int u = tid + (it << 8);
        vU[it] = (u < 448);
        int uu = vU[it] ? u : 0;
        nU[it] = uu % 112; gU[it] = uu / 112;
        int gn = nb * 112 + nU[it];
        pbU[it] = min(gn, NREAL - 1);
    }
    const ushort* BHz = BH + (size_t)z * PLSTR;
    const ushort* BLz = BL + (size_t)z * PLSTR;

    floatx4 acc[2][7];
#pragma unroll
    for (int mf = 0; mf < 2; ++mf)
#pragma unroll
        for (int nf = 0; nf < 7; ++nf) acc[mf][nf] = (floatx4){0.f, 0.f, 0.f, 0.f};

    short8 rbh[2], rbl[2];

#define STAGE_ISSUE(KST, BUF) { \
    int k8 = (KST) * 4; \
    _Pragma("unroll") \
    for (int j = 0; j < 4; ++j) { \
        int h = wv * 4 + j, p = h >> 3, g = (h >> 1) & 3, hf = h & 1; \
        gll16(WA + (p ? ALO : 0) + (long)(k8 + g) * MTOT + m0 + hf * 64 + lane, \
              L + (BUF) * 1936 + (p * 4 + g) * 129 + hf * 64); \
    } \
    int ci0 = (KST) << 5; \
    _Pragma("unroll") \
    for (int it = 0; it < 2; ++it) if (vU[it]) { \
        size_t o = (size_t)pbU[it] * KW + ci0 + gU[it] * 8; \
        rbh[it] = *(const short8*)(BHz + o); \
        rbl[it] = *(const short8*)(BLz + o); \
    } }

#define STAGE_WRITE(BUF) { \
    _Pragma("unroll") \
    for (int it = 0; it < 2; ++it) if (vU[it]) { \
        *((short8*)(L + (BUF) * 1936 + 1032 + gU[it] * 113 + nU[it])) = rbh[it]; \
        *((short8*)(L + (BUF) * 1936 + 1484 + gU[it] * 113 + nU[it])) = rbl[it]; \
    } }

#define COMPUTE(BUF) { \
    const int4* Lc = L + (BUF) * 1936; \
    short8 ah[2], al[2]; \
    _Pragma("unroll") \
    for (int mf = 0; mf < 2; ++mf) { \
        int au = lrow * 129 + (wv * 2 + mf) * 16 + lcol; \
        ah[mf] = *(const short8*)(Lc + au); \
        al[mf] = *(const short8*)(Lc + 516 + au); \
    } \
    _Pragma("unroll") \
    for (int nf = 0; nf < 7; ++nf) { \
        int bu = 1032 + lrow * 113 + nf * 16 + lcol; \
        short8 bh = *(const short8*)(Lc + bu); \
        short8 bl = *(const short8*)(Lc + bu + 452); \
        _Pragma("unroll") \
        for (int mf = 0; mf < 2; ++mf) { MFMA3(acc[mf][nf], ah[mf], al[mf], bh, bl) } \
    } }

    STAGE_ISSUE(0, 0)
    STAGE_WRITE(0)
    __syncthreads();

    int cur = 0;
    for (int kst = 0; kst < KSTN; ++kst) {
        int nxt = cur ^ 1;
        bool more = (kst + 1 < KSTN);
        if (more) STAGE_ISSUE(kst + 1, nxt)
        COMPUTE(cur)
        if (more) { STAGE_WRITE(nxt) __syncthreads(); }
        cur = nxt;
    }

#pragma unroll
    for (int mf = 0; mf < 2; ++mf) {
        int m = m0 + wv * 32 + mf * 16 + lrow * 4;
#pragma unroll
        for (int nf = 0; nf < 7; ++nf) {
            int col = nf * 16 + lcol;
            int gn = nb * 112 + col;
            if (gn < NREAL) {
#pragma unroll
                for (int r = 0; r < 4; ++r) {
                    size_t idx = ((size_t)z * MTOT + m + r) * NREAL + gn;
                    Y[idx] = acc[mf][nf][r];
                }
            }
        }
    }
#undef STAGE_ISSUE
#undef STAGE_WRITE
#undef COMPUTE
}

// ---- weight prep: 3x3 convs [512][ci*9+tap] -> [576][512][8] hi/lo, K-order (cb,tap,ci) ----
__global__ void prep_w_k(const float* __restrict__ s0, const float* __restrict__ s1,
                         const float* __restrict__ s2, const float* __restrict__ s3,
                         int4* __restrict__ dst)
{
    const int c = blockIdx.y;
    const float* src = (c == 0) ? s0 : (c == 1) ? s1 : (c == 2) ? s2 : s3;
    int4* dh = dst + (size_t)c * 589824;
    int4* dl = dh + 294912;
    int idx = blockIdx.x * 256 + threadIdx.x;
    if (idx >= 294912) return;
    int g8 = idx / 512, m = idx & 511;
    unsigned hw[4], lw[4];
#pragma unroll
    for (int j = 0; j < 4; ++j) {
        int k1 = g8 * 8 + 2 * j, k2 = k1 + 1;
        int cb1 = k1 / 288, r1 = k1 % 288, tp1 = r1 >> 5, ci1 = cb1 * 32 + (r1 & 31);
        int cb2 = k2 / 288, r2 = k2 % 288, tp2 = r2 >> 5, ci2 = cb2 * 32 + (r2 & 31);
        float v1 = src[(size_t)m * 4608 + ci1 * 9 + tp1];
        float v2 = src[(size_t)m * 4608 + ci2 * 9 + tp2];
        unsigned short h0, l0, h1, l1;
        split2(v1, h0, l0); split2(v2, h1, l1);
        hw[j] = (unsigned)h0 | ((unsigned)h1 << 16);
        lw[j] = (unsigned)l0 | ((unsigned)l1 << 16);
    }
    dh[idx] = make_int4(hw[0], hw[1], hw[2], hw[3]);
    dl[idx] = make_int4(lw[0], lw[1], lw[2], lw[3]);
}

// ---------------- weight prep: plain GEMM A [M][ldw] -> [K/8][M][8] hi/lo ----------------
__global__ void prep_wg_k(const float* __restrict__ src, int ldw, int M, int K8,
                          int4* __restrict__ dst)
{
    int idx = blockIdx.x * 256 + threadIdx.x;
    if (idx >= K8 * M) return;
    int g8 = idx / M, m = idx % M;
    unsigned hw[4], lw[4];
#pragma unroll
    for (int j = 0; j < 4; ++j) {
        int k1 = g8 * 8 + 2 * j;
        float v1 = src[(size_t)m * ldw + k1];
        float v2 = src[(size_t)m * ldw + k1 + 1];
        unsigned short h0, l0, h1, l1;
        split2(v1, h0, l0); split2(v2, h1, l1);
        hw[j] = (unsigned)h0 | ((unsigned)h1 << 16);
        lw[j] = (unsigned)l0 | ((unsigned)l1 << 16);
    }
    dst[idx] = make_int4(hw[0], hw[1], hw[2], hw[3]);
    dst[(size_t)K8 * M + idx] = make_int4(lw[0], lw[1], lw[2], lw[3]);
}

// ---------------- transpose + split: src [C][S] fp32 -> dst [S][C] bf16 hi/lo ----------------
__global__ __launch_bounds__(256)
void tsplit_k(const float* __restrict__ src, ushort* __restrict__ dh, ushort* __restrict__ dl,
              int C, int S, long zsrc, long zdst)
{
    __shared__ float t[64][65];
    const int c0 = blockIdx.x * 64, s0 = blockIdx.y * 64, z = blockIdx.z;
    const float* sz = src + (size_t)z * zsrc;
    const int tx = threadIdx.x & 63, ty = threadIdx.x >> 6;
#pragma unroll
    for (int i = 0; i < 16; ++i) {
        int cc = i * 4 + ty;
        int c = c0 + cc, s = s0 + tx;
        t[cc][tx] = (c < C && s < S) ? sz[(size_t)c * S + s] : 0.f;
    }
    __syncthreads();
#pragma unroll
    for (int i = 0; i < 16; ++i) {
        int ss = i * 4 + ty;
        int s = s0 + ss, c = c0 + tx;
        if (s < S && c < C) {
            unsigned short h, l;
            split2(t[tx][ss], h, l);
            size_t o = (size_t)z * zdst + (size_t)s * C + c;
            dh[o] = h; dl[o] = l;
        }
    }
}

// ---------------- conv2 B prestage: relu(bg[b] + bias1[z])^T -> [z][472][512] hi/lo ----------------
__global__ __launch_bounds__(256)
void tsplit_c2_k(const float* __restrict__ bg, const float* __restrict__ bias1,
                 ushort* __restrict__ dh, ushort* __restrict__ dl)
{
    __shared__ float t[64][65];
    const int c0 = blockIdx.x * 64, s0 = blockIdx.y * 64, z = blockIdx.z;
    const int b = z / RR;
    const int tx = threadIdx.x & 63, ty = threadIdx.x >> 6;
#pragma unroll
    for (int i = 0; i < 16; ++i) {
        int cc = i * 4 + ty;
        int s = s0 + tx;
        t[cc][tx] = (s < 464) ? bg[((size_t)b * 512 + c0 + cc) * 464 + s] : 0.f;
    }
    __syncthreads();
    const float bv = bias1[z * 512 + c0 + tx];
#pragma unroll
    for (int i = 0; i < 16; ++i) {
        int ss = i * 4 + ty;
        int s = s0 + ss, c = c0 + tx;
        if (s < 472) {
            float v = (s < 464) ? fmaxf(t[tx][ss] + bv, 0.f) : 0.f;
            unsigned short h, l;
            split2(v, h, l);
            size_t o = (size_t)z * 241664 + (size_t)s * 512 + c;
            dh[o] = h; dl[o] = l;
        }
    }
}

// ---------------- hr2o B prestage: pad 7x14 -> [z][160 sp][512 ci] hi/lo ----------------
__global__ __launch_bounds__(256)
void tsplit_pad_k(const float* __restrict__ x, ushort* __restrict__ dh, ushort* __restrict__ dl)
{
    __shared__ float t[64 * 99];
    const int c0 = blockIdx.x * 64, z = blockIdx.y;
    const int tid = threadIdx.x;
#pragma unroll
    for (int i = 0; i < 25; ++i) {
        int idx = tid + i * 256;
        if (idx < 6272) {
            int c = idx / 98, s = idx % 98;
            t[c * 99 + s] = x[((size_t)z * 512 + c0 + c) * 98 + s];
        }
    }
    __syncthreads();
#pragma unroll
    for (int i = 0; i < 40; ++i) {
        int idx = tid + i * 256;   // < 10240 = 160*64
        int sp = idx >> 6, c = idx & 63;
        int r = sp >> 4, col = sp & 15;
        float v = (r >= 1 && r <= 7 && col >= 1 && col <= 14) ? t[c * 99 + (r - 1) * 14 + col - 1] : 0.f;
        unsigned short h, l;
        split2(v, h, l);
        size_t o = (size_t)z * 81920 + (size_t)sp * 512 + c0 + c;
        dh[o] = h; dl[o] = l;
    }
}

// ---------------- temporal mean ----------------
__global__ void tmean_k(const float* __restrict__ f, float* __restrict__ o, int total)
{
    int i = blockIdx.x * blockDim.x + threadIdx.x;
    if (i >= total) return;
    int p = i % HWIN; long bc = i / HWIN;
    const float* src = f + bc * (long)TT * HWIN + p;
    o[i] = (src[0] + src[HWIN] + src[2 * HWIN] + src[3 * HWIN]) * 0.25f;
}

// ---------------- ROI align ----------------
__global__ __launch_bounds__(256)
void roi_align_k(const float* __restrict__ feats, const float* __restrict__ rois,
                 float* __restrict__ roi_feats)
{
    __shared__ int s_o00[196], s_o01[196], s_o10[196], s_o11[196];
    __shared__ float s_w[4][196];
    const int n = blockIdx.x;
    const int b = n / RR;
    const int t = threadIdx.x;
    if (t < 196) {
        float x1 = rois[n * 4 + 0] * WW, y1 = rois[n * 4 + 1] * HH;
        float x2 = rois[n * 4 + 2] * WW, y2 = rois[n * 4 + 3] * HH;
        float rw = fmaxf(x2 - x1, 1.f), rh = fmaxf(y2 - y1, 1.f);
        float bw = rw / 7.f, bh = rh / 7.f;
        int j = t / 14, i = t % 14;
        float gy = (float)(j >> 1) + ((j & 1) + 0.5f) * 0.5f;
        float gx = (float)(i >> 1) + ((i & 1) + 0.5f) * 0.5f;
        float ys = y1 + gy * bh, xs = x1 + gx * bw;
        bool valid = (ys >= -1.f) && (ys <= (float)HH) && (xs >= -1.f) && (xs <= (float)WW);
        float y = fminf(fmaxf(ys, 0.f), (float)(HH - 1));
        float x = fminf(fmaxf(xs, 0.f), (float)(WW - 1));
        float y0f = floorf(y), x0f = floorf(x);
        int iy0 = (int)y0f, ix0 = (int)x0f;
        int iy1 = min(iy0 + 1, HH - 1), ix1 = min(ix0 + 1, WW - 1);
        float ly = y - y0f, lx = x - x0f, hy = 1.f - ly, hx = 1.f - lx;
        float msk = valid ? 1.f : 0.f;
        s_o00[t] = iy0 * WW + ix0; s_o01[t] = iy0 * WW + ix1;
        s_o10[t] = iy1 * WW + ix0; s_o11[t] = iy1 * WW + ix1;
        s_w[0][t] = hy * hx * msk; s_w[1][t] = hy * lx * msk;
        s_w[2][t] = ly * hx * msk; s_w[3][t] = ly * lx * msk;
    }
    __syncthreads();
    for (int c = t; c < REDUCE; c += 256) {
        const float* img = feats + ((long)(b * REDUCE + c)) * HWIN;
        float mx = -INFINITY;
        for (int bin = 0; bin < 49; ++bin) {
            int by_ = bin / 7, bx = bin % 7;
            float s = 0.f;
#pragma unroll
            for (int sy = 0; sy < 2; ++sy)
#pragma unroll
                for (int sx = 0; sx < 2; ++sx) {
                    int ss = (by_ * 2 + sy) * 14 + bx * 2 + sx;
                    s += s_w[0][ss] * img[s_o00[ss]] + s_w[1][ss] * img[s_o01[ss]]
                       + s_w[2][ss] * img[s_o10[ss]] + s_w[3][ss] * img[s_o11[ss]];
                }
            mx = fmaxf(mx, s * 0.25f);
        }
        roi_feats[(long)n * REDUCE + c] = mx;
    }
}

// ---------------- small dense dots ----------------
__global__ void dots_k(const float* __restrict__ Xr, const float* __restrict__ Wt,
                       int ldw, int woff, float* __restrict__ Y,
                       int Nrows, int M, int K, int relu)
{
    int idx = blockIdx.x * blockDim.x + threadIdx.x;
    if (idx >= Nrows * M) return;
    int o = idx / Nrows, n = idx % Nrows;
    const float* xr = Xr + (long)n * K;
    const float* w = Wt + (long)o * ldw + woff;
    float acc = 0.f;
    for (int k = 0; k < K; ++k) acc = fmaf(xr[k], w[k], acc);
    if (relu) acc = fmaxf(acc, 0.f);
    Y[(long)n * M + o] = acc;
}

// ---------------- maxpool 3x3 s2 pad1 ----------------
__global__ void maxpool_k(const float* __restrict__ in, float* __restrict__ out, int total)
{
    int idx = blockIdx.x * blockDim.x + threadIdx.x;
    if (idx >= total) return;
    int ow = idx % PW; int r = idx / PW; int oh = r % PH; long nc = r / PH;
    const float* src = in + nc * NSP2;
    float m = -INFINITY;
    for (int kh = 0; kh < 3; ++kh) {
        int ih = oh * 2 - 1 + kh; if (ih < 0 || ih >= OH2) continue;
        for (int kw = 0; kw < 3; ++kw) {
            int iw = ow * 2 - 1 + kw; if (iw < 0 || iw >= OW2) continue;
            m = fmaxf(m, src[ih * OW2 + iw]);
        }
    }
    out[idx] = m;
}

// ---------------- fused attention scores + softmax ----------------
__global__ __launch_bounds__(256)
void att2_k(const float* __restrict__ q, const float* __restrict__ k, float* __restrict__ att)
{
    __shared__ float qs[5376];
    __shared__ float ks[5376];
    __shared__ float sc[1008];
    const int b = blockIdx.x, p0 = blockIdx.y * 7;
    const int tid = threadIdx.x;

    int itI[4], itJ[4], itP[4]; bool itV[4];
#pragma unroll
    for (int r = 0; r < 4; ++r) {
        int item = tid + (r << 8);
        itV[r] = item < 1008;
        int it = itV[r] ? item : 0;
        int ij = it / 7; itP[r] = it % 7;
        itI[r] = ij / 12; itJ[r] = ij % 12;
    }
    float acc[4] = {0.f, 0.f, 0.f, 0.f};

    for (int cc0 = 0; cc0 < 512; cc0 += 64) {
        for (int l = tid; l < 5376; l += 256) {
            int i = l / 448, r = l % 448, c = r / 7, p = r % 7;
            size_t off = ((size_t)(b * 12 + i) * 512 + cc0 + c) * 98 + p0 + p;
            qs[l] = q[off];
            ks[l] = k[off];
        }
        __syncthreads();
#pragma unroll
        for (int r = 0; r < 4; ++r) {
            if (itV[r]) {
                const float* qp = qs + itI[r] * 448 + itP[r];
                const float* kp = ks + itJ[r] * 448 + itP[r];
                float a = acc[r];
#pragma unroll 8
                for (int c = 0; c < 64; ++c) a = fmaf(qp[c * 7], kp[c * 7], a);
                acc[r] = a;
            }
        }
        __syncthreads();
    }
#pragma unroll
    for (int r = 0; r < 4; ++r)
        if (itV[r]) sc[tid + (r << 8)] = acc[r] * ATT_SCALE;
    __syncthreads();
    if (tid < 84) {
        int i = tid / 7, p = tid % 7;
        float m = -INFINITY;
        float v[12];
#pragma unroll
        for (int j = 0; j < 12; ++j) { v[j] = sc[(i * 12 + j) * 7 + p]; m = fmaxf(m, v[j]); }
        float s = 0.f;
#pragma unroll
        for (int j = 0; j < 12; ++j) { v[j] = expf(v[j] - m); s += v[j]; }
        float inv = 1.f / s;
#pragma unroll
        for (int j = 0; j < 12; ++j)
            att[((size_t)(b * 12 + i) * 12 + j) * 98 + p0 + p] = v[j] * inv;
    }
}

// ---------------- virt = att @ v ----------------
__global__ __launch_bounds__(256)
void virt2_k(const float* __restrict__ att, const float* __restrict__ v, float* __restrict__ virt)
{
    __shared__ float as_[14112];
    const int b = blockIdx.x, cb = blockIdx.y;
    const int tid = threadIdx.x;
    for (int l = tid; l < 14112; l += 256) as_[l] = att[(size_t)b * 14112 + l];
    __syncthreads();

    for (int it = tid; it < 6272; it += 256) {
        int c = cb * 64 + it / 98, p = it % 98;
        float o[12];
#pragma unroll
        for (int i = 0; i < 12; ++i) o[i] = 0.f;
#pragma unroll
        for (int j = 0; j < 12; ++j) {
            float vj = v[((size_t)(b * 12 + j) * 512 + c) * 98 + p];
#pragma unroll
            for (int i = 0; i < 12; ++i) o[i] = fmaf(as_[(i * 12 + j) * 98 + p], vj, o[i]);
        }
#pragma unroll
        for (int i = 0; i < 12; ++i)
            virt[((size_t)(b * 12 + i) * 512 + c) * 98 + p] = o[i];
    }
}

// ---------------- per-actor stats ----------------
__global__ __launch_bounds__(256)
void stats_k(const float* __restrict__ virt, float* __restrict__ mu, float* __restrict__ rstd)
{
    int n = blockIdx.x;
    const float* src = virt + (long)n * HID * NSP;
    float s = 0.f, q = 0.f;
    for (int i = threadIdx.x; i < HID * NSP; i += 256) {
        float v = src[i]; s += v; q = fmaf(v, v, q);
    }
    for (int off = 32; off; off >>= 1) { s += __shfl_down(s, off); q += __shfl_down(q, off); }
    __shared__ float ss[4], sq[4];
    int w = threadIdx.x >> 6;
    if ((threadIdx.x & 63) == 0) { ss[w] = s; sq[w] = q; }
    __syncthreads();
    if (threadIdx.x == 0) {
        float S = ss[0] + ss[1] + ss[2] + ss[3];
        float Q = sq[0] + sq[1] + sq[2] + sq[3];
        const float invN = 1.f / (HID * NSP);
        float m = S * invN;
        float var = Q * invN - m * m;
        mu[n] = m; rstd[n] = rsqrtf(var + 1e-5f);
    }
}

// ---------------- normalize + affine + relu ----------------
__global__ void norm_k(float* __restrict__ virt, const float* __restrict__ mu,
                       const float* __restrict__ rstd,
                       const float* __restrict__ gamma, const float* __restrict__ beta)
{
    int idx = blockIdx.x * blockDim.x + threadIdx.x;
    const int TOT = NIMG * HID * NSP;
    if (idx >= TOT) return;
    int n = idx / (HID * NSP);
    int c = (idx / NSP) % HID;
    float val = (virt[idx] - mu[n]) * rstd[n] * gamma[c] + beta[c];
    virt[idx] = fmaxf(val, 0.f);
}

// ---------------- spatial mean ----------------
__global__ void meanpool_k(const float* __restrict__ x, float* __restrict__ high)
{
    int idx = blockIdx.x * blockDim.x + threadIdx.x;
    if (idx >= NIMG * HID) return;
    const float* src = x + (long)idx * NSP;
    float s = 0.f;
    for (int p = 0; p < NSP; ++p) s += src[p];
    high[idx] = s * (1.f / NSP);
}

// ---------------- final FC ----------------
__global__ void final_k(const float* __restrict__ fc1o, const float* __restrict__ high,
                        const float* __restrict__ fc2, float* __restrict__ out)
{
    int idx = blockIdx.x * blockDim.x + threadIdx.x;
    if (idx >= NIMG * NC) return;
    int n = idx / NC, o = idx % NC;
    const float* w = fc2 + (long)o * (2 * HID);
    const float* a = fc1o + (long)n * HID;
    const float* h = high + (long)n * HID;
    float acc = 0.f;
    for (int c = 0; c < HID; ++c) acc = fmaf(a[c], w[c], acc);
    for (int c = 0; c < HID; ++c) acc = fmaf(h[c], w[HID + c], acc);
    out[idx] = acc;
}

// ---------------- launcher ----------------
extern "C" void kernel_launch(void* const* d_in, const int* in_sizes, int n_in,
                              void* d_out, int out_size, void* d_ws, size_t ws_size,
                              hipStream_t stream)
{
    (void)in_sizes; (void)n_in; (void)out_size; (void)ws_size;
    const float* features = (const float*)d_in[0];
    const float* rois     = (const float*)d_in[1];
    const float* w_reduce = (const float*)d_in[2];
    const float* w_conv1  = (const float*)d_in[3];
    const float* w_conv2  = (const float*)d_in[4];
    const float* qw       = (const float*)d_in[5];
    const float* kw       = (const float*)d_in[6];
    const float* vw       = (const float*)d_in[7];
    const float* cw       = (const float*)d_in[8];
    const float* gamma    = (const float*)d_in[9];
    const float* beta     = (const float*)d_in[10];
    const float* fc1      = (const float*)d_in[11];
    const float* fc2      = (const float*)d_in[12];
    float* ws = (float*)d_ws;

    // ---- workspace layout (floats), high-water ~62.0M = 248 MB ----
    float*  tmean = ws + 0;
    ushort* tmTH  = (ushort*)(ws + 8552448);
    ushort* tmTL  = (ushort*)(ws + 12828672);
    float*  feats = ws + 17104896;
    ushort* ftTH  = (ushort*)(ws + 0);
    ushort* ftTL  = (ushort*)(ws + 1900544);
    ushort* B2H   = (ushort*)(ws + 0);
    ushort* B2L   = (ushort*)(ws + 11599872);
    int4*   WTQ   = (int4*)(ws + 0);
    float*  bg    = ws + 23199744;
    float*  out2  = ws + 23199744;
    float*  qb    = ws + 23199744;     // also: cw split-K partial 0 (dead after att2)
    float*  kb    = ws + 28016640;     // also: cw split-K partial 1
    float*  vb    = ws + 32833536;
    ushort* PTH   = (ushort*)(ws + 41779200);
    ushort* PTL   = (ushort*)(ws + 45711360);
    float*  xb    = ws + 49643520;
    float*  virt  = ws + 54460416;
    int4*   WTS   = (int4*)(ws + 59277312);
    float*  rf    = ws + 61636608;
    float*  bias1 = ws + 61734912;
    float*  fc1o  = ws + 61784064;
    float*  attb  = ws + 61833216;
    float*  mu    = ws + 61946112;
    float*  rstd  = ws + 61946240;
    float*  high  = ws + 61946368;

    dim3 blk(256);

    // 0. reduce-conv weight prep
    prep_wg_k<<<1152, blk, 0, stream>>>(w_reduce, 2304, 1024, 288, WTS);

    // 1. temporal mean
    { int tot = BB * WIDTH * HWIN;
      tmean_k<<<(tot + 255) / 256, blk, 0, stream>>>(features, tmean, tot); }

    // 2. transpose+split tmean
    tsplit_k<<<dim3(36, 8, 8), blk, 0, stream>>>(tmean, tmTH, tmTL, 2304, 464, 1069056, 1069056);

    // 3. reduce conv (MFMA GEMM)
    tapc_k<2304, 72, 1024, 464L * 2304, 464>
        <<<dim3(5, 8, 8), blk, 0, stream>>>(WTS, tmTH, tmTL, feats);

    // 4. transpose+split feats
    tsplit_k<<<dim3(16, 8, 8), blk, 0, stream>>>(feats, ftTH, ftTL, 1024, 464, 475136, 475136);

    // 5. ROI align + actor bias + fc1
    roi_align_k<<<96, blk, 0, stream>>>(feats, rois, rf);
    dots_k<<<(NIMG * HID + 255) / 256, blk, 0, stream>>>(rf, w_conv1, 2048, 1024, bias1, NIMG, HID, REDUCE, 0);
    dots_k<<<(NIMG * HID + 255) / 256, blk, 0, stream>>>(rf, fc1, 1024, 0, fc1o, NIMG, HID, REDUCE, 1);

    // 6. bg GEMM
    prep_wg_k<<<256, blk, 0, stream>>>(w_conv1, 2048, 512, 128, WTS);
    tapc_k<1024, 32, 512, 464L * 1024, 464>
        <<<dim3(5, 4, 8), blk, 0, stream>>>(WTS, ftTH, ftTL, bg);

    // 7. conv2 weight prep (cb-tap-ci order) + B prestage
    prep_w_k<<<dim3(1152, 1), blk, 0, stream>>>(w_conv2, w_conv2, w_conv2, w_conv2, WTS);
    tsplit_c2_k<<<dim3(8, 8, 96), blk, 0, stream>>>(bg, bias1, B2H, B2L);

    // 8. conv2: champion config (768 blocks: 4 ch x 4 nb x 48 zp)
    tapr_k<1, 1, true, false, 165, 2, 1><<<768, blk, 0, stream>>>(
        WTS, nullptr, nullptr, B2H, B2L, nullptr, out2, nullptr, nullptr);

    // 9. maxpool
    { int tot = NIMG * HID * NSP;
      maxpool_k<<<(tot + 255) / 256, blk, 0, stream>>>(out2, xb, tot); }

    // 10. HR2O layers
    for (int d = 0; d < DEPTH; ++d) {
        long woff = (long)d * HID * HID * 9;
        prep_w_k<<<dim3(1152, 4), blk, 0, stream>>>(qw + woff, kw + woff, vw + woff, cw + woff, WTQ);

        tsplit_pad_k<<<dim3(8, 96), blk, 0, stream>>>(xb, PTH, PTL);
        // qkv: champion config (576 blocks: 12 ch x 48 zp)
        tapr_k<0, 3, false, false, 161, 2, 1><<<576, blk, 0, stream>>>(
            WTQ, WTQ + 589824, WTQ + 2 * 589824, PTH, PTL, nullptr, qb, kb, vb);

        att2_k<<<dim3(8, 14), blk, 0, stream>>>(qb, kb, attb);
        virt2_k<<<dim3(8, 8), blk, 0, stream>>>(attb, vb, virt);
        stats_k<<<96, blk, 0, stream>>>(virt, mu, rstd);
        { int tot = NIMG * HID * NSP;
          norm_k<<<(tot + 255) / 256, blk, 0, stream>>>(virt, mu, rstd, gamma + d * HID, beta + d * HID); }

        tsplit_pad_k<<<dim3(8, 96), blk, 0, stream>>>(virt, PTH, PTL);
        // cw: split-K x2, ZB=1 (grid 768 = 2 kh x 4 ch x 96 z) -> partials in qb/kb (dead)
        tapr_k<0, 1, false, false, 161, 1, 2><<<768, blk, 0, stream>>>(
            WTQ + 3 * 589824, nullptr, nullptr, PTH, PTL, nullptr, qb, kb, nullptr);
        { int tot = NIMG * HID * NSP;
          merge_k<<<(tot + 255) / 256, blk, 0, stream>>>(xb, qb, kb, tot); }
    }

    // 11. spatial mean + final FC
    meanpool_k<<<(NIMG * HID + 255) / 256, blk, 0, stream>>>(xb, high);
    final_k<<<(NIMG * NC + 255) / 256, blk, 0, stream>>>(fc1o, high, fc2, (float*)d_out);
}